// Round 12
// baseline (133.508 us; speedup 1.0000x reference)
//
#include <hip/hip_runtime.h>

// Problem constants (fixed by the reference file).
#define DIN  4096
#define NG   4096          // NUM_GATES = DOUT/3
#define BS   4096
#define RPB  16            // rows per block -> 256 blocks = 1 per CU
#define BT   1024          // 16 waves
#define NW   16
#define WFL  832           // floats staged per wave per row: 3x dma16 + 1x dma4

// Builtin (TRACKED) waits. gfx9 imm16: vmcnt[3:0]=bits[3:0], vmcnt[5:4]=bits
// [15:14], exp=bits[6:4], lgkm=bits[11:8]. 0x0F70 leaves lgkm/exp free.
#define WAITVM(N)  __builtin_amdgcn_s_waitcnt((N) | 0x0F70)
#define WAITVM16() __builtin_amdgcn_s_waitcnt(0x4F70)        // vmcnt(16)

// Async global->LDS DMA (TRACKED). LDS dest = wave-uniform base + lane*size;
// global src is per-lane (row-wrap &4095 done per lane). size is a literal.
__device__ __forceinline__ void dma16(const float* g, float* lds) {
    __builtin_amdgcn_global_load_lds(
        (const __attribute__((address_space(1))) void*)g,
        (__attribute__((address_space(3))) void*)lds, 16, 0, 0);
}
__device__ __forceinline__ void dma4(const float* g, float* lds) {
    __builtin_amdgcn_global_load_lds(
        (const __attribute__((address_space(1))) void*)g,
        (__attribute__((address_space(3))) void*)lds, 4, 0, 0);
}

// out[b,g] = w0*x[b,(3g+1)&4095] + w1*x[b,(3g+2)&4095] + w2*x[b,(3g+3)&4095] + w3
// (w0..w3) = softmax(wgts[g,0,0..3]). Reference's signals[:, :, ::3] selects only
// row 0 of M = [1,0,0,0,0] -> out = s[...,0]; v4/v5 and rows 1..2 are dead code.
//
// R17: barrier-free wave-private staging + ring-3 counted-vmcnt pipeline,
// ALL vmem ops tracked (builtin DMA + builtin waits).
//  - Ledger: tracked-regime kernels (R8/R11/R12/R13) were ALL correct,
//    including store-inclusive counts -> tracked vmcnt retirement behaves
//    in-order. The asm-load arc (R14/R15/R16) failed correctness 3x
//    (SIInsertWaitcnts deletes builtin waits it models as redundant; raw
//    waits still leaked) -> abandoned per pre-registration.
//  - Fast tracked kernels (R8/R13 ~29 us) paid 8x 16-wave barriers; R12
//    proved wave-private windows need NO barrier but serialized on a
//    2-object/distance-1 ring (compiler conservative drain). This kernel:
//    3 separate LDS objects, stage distance 2, zero barriers.
//  - Wave v owns gates [256v,256v+256); x-footprint = contiguous wrapped
//    window x[768v..768v+831] staged into ITS slice of the ring buffer.
//    No cross-wave sharing -> wave waits only its OWN (tracked) vmcnt.
//  - Ring: iter r computes W[r%3], stages row r+2 into W[(r+2)%3] (= the
//    buffer read at iter r-1; its ds_reads were consumed into VGPRs before
//    iter r-1's FMAs, which precede this stage in program order -> no WAW).
//  - Exact NWAIT (ops/iter: 4 DMA + 4 stores; D_r issued at iter r-2):
//    it0: D1,D2                      ->  8
//    it1: D2,S0,D3                   -> 12
//    it2..13: S_{r-2},D_{r+1},S_{r-1},D_{r+2} -> 16  (hi-bit encoding)
//    it14: S12,D15,S13               -> 12
//    it15: S13,S14                   ->  8
//  - LDS 3 x 16 x 832 x 4B = 159744 B -> 1 block/CU (AITER attn uses 160KB
//    blocks on gfx950, so the size is launchable). 16 waves x 8 vmem in
//    flight ~ 106 KB/CU >> ~9 KB bandwidth-delay product per CU.
//  - LDS reads dword-stride-3 (bank 3l+1 mod 32, 2-way = free); stores
//    4 x 256B coalesced wave stores; fetch-once per row by one CU.
__global__ __launch_bounds__(BT, 4) void fredkin_ring3(
    const float* __restrict__ x,
    const float* __restrict__ wgts,
    float* __restrict__ out)
{
    // 3 SEPARATE objects so LLVM's per-object LDS-DMA tracking doesn't
    // conservatively drain other buffers' outstanding DMAs (R8 lesson;
    // R12's 2-object version serialized).
    __shared__ float LA[NW * WFL];
    __shared__ float LB[NW * WFL];
    __shared__ float LC[NW * WFL];

    const int tid = threadIdx.x;
    const int v   = tid >> 6;        // wave 0..15 (uniform per wave)
    const int l   = tid & 63;        // lane
    const int row0 = blockIdx.x * RPB;

    // Softmax of wgts[g,0,:] for gates g = 256v + l + 64k. Fully consumed
    // before the first DMA (tracked loads; compiler orders them correctly).
    float4 wq[4];
#pragma unroll
    for (int k = 0; k < 4; ++k) {
        const int g = (v << 8) + l + (k << 6);
        float4 r = *reinterpret_cast<const float4*>(wgts + (size_t)g * 12);
        float m  = fmaxf(fmaxf(r.x, r.y), fmaxf(r.z, r.w));
        float e0 = __expf(r.x - m);
        float e1 = __expf(r.y - m);
        float e2 = __expf(r.z - m);
        float e3 = __expf(r.w - m);
        float inv = 1.0f / (e0 + e1 + e2 + e3);
        wq[k] = make_float4(e0 * inv, e1 * inv, e2 * inv, e3 * inv);
    }

    // Per-lane wrapped source offsets (floats) for the 4 DMA ops of a row.
    // Window of wave v = x[(768v + t) & 4095], t = 0..831, staged linearly.
    const int wb = 3 * (v << 8);                  // 768v
    const int s0 = (wb       + (l << 2)) & (DIN - 1);
    const int s1 = (wb + 256 + (l << 2)) & (DIN - 1);
    const int s2 = (wb + 512 + (l << 2)) & (DIN - 1);
    const int s3 = (wb + 768 +  l      ) & (DIN - 1);

    float* W0 = LA + v * WFL;   // this wave's slice of each ring buffer
    float* W1 = LB + v * WFL;
    float* W2 = LC + v * WFL;

#define STAGE(DST, R_) {                                              \
        const float* xr = x + (size_t)(row0 + (R_)) * DIN;            \
        dma16(xr + s0, (DST));                                        \
        dma16(xr + s1, (DST) + 256);                                  \
        dma16(xr + s2, (DST) + 512);                                  \
        dma4 (xr + s3, (DST) + 768);                                  \
    }

    asm volatile("" ::: "memory");
    STAGE(W0, 0)                  // prologue: rows 0,1 in flight (depth 2)
    STAGE(W1, 1)

    // Gate g = 256v + l + 64k reads staged floats t..t+2, t = 3l + 192k + 1
    // (max index 768 at l=63,k=3 — inside the dma4 tail). 2-way banks = free.
    const int t1 = 3 * l + 1;

#define FRED_ITER(R_, CUR, STG, DO_STAGE, WAITEXPR)                           \
    {                                                                         \
        if (DO_STAGE) STAGE(STG, (R_) + 2)                                    \
        asm volatile("" ::: "memory");                                        \
        WAITEXPR;                   /* own DMA(R_) retired (tracked) */       \
        asm volatile("" ::: "memory");                                        \
        float* orow = out + (size_t)(row0 + (R_)) * NG + (v << 8) + l;        \
        _Pragma("unroll")                                                     \
        for (int k = 0; k < 4; ++k) {                                         \
            const float* p = (CUR) + t1 + 192 * k;                            \
            float o = fmaf(wq[k].x, p[0],                                     \
                      fmaf(wq[k].y, p[1],                                     \
                      fmaf(wq[k].z, p[2], wq[k].w)));                         \
            __builtin_nontemporal_store(o, orow + (k << 6));                  \
        }                                                                     \
    }

    FRED_ITER( 0, W0, W2, 1, WAITVM(8))
    FRED_ITER( 1, W1, W0, 1, WAITVM(12))
    FRED_ITER( 2, W2, W1, 1, WAITVM16())
    FRED_ITER( 3, W0, W2, 1, WAITVM16())
    FRED_ITER( 4, W1, W0, 1, WAITVM16())
    FRED_ITER( 5, W2, W1, 1, WAITVM16())
    FRED_ITER( 6, W0, W2, 1, WAITVM16())
    FRED_ITER( 7, W1, W0, 1, WAITVM16())
    FRED_ITER( 8, W2, W1, 1, WAITVM16())
    FRED_ITER( 9, W0, W2, 1, WAITVM16())
    FRED_ITER(10, W1, W0, 1, WAITVM16())
    FRED_ITER(11, W2, W1, 1, WAITVM16())
    FRED_ITER(12, W0, W2, 1, WAITVM16())
    FRED_ITER(13, W1, W0, 1, WAITVM16())
    FRED_ITER(14, W2, W1, 0, WAITVM(12))
    FRED_ITER(15, W0, W2, 0, WAITVM(8))
#undef FRED_ITER
#undef STAGE
}

extern "C" void kernel_launch(void* const* d_in, const int* in_sizes, int n_in,
                              void* d_out, int out_size, void* d_ws, size_t ws_size,
                              hipStream_t stream) {
    const float* x    = (const float*)d_in[0];   // (BS, DIN) fp32
    const float* wgts = (const float*)d_in[1];   // (NG, 3, 4) fp32
    // d_in[2] (connections) is deterministic: (3g+1+j) % DIN — computed inline.
    float* out = (float*)d_out;                  // (BS, NG) fp32

    fredkin_ring3<<<dim3(BS / RPB), dim3(BT), 0, stream>>>(x, wgts, out);
}

// Round 13
// 126.040 us; speedup vs baseline: 1.0593x; 1.0593x over previous
//
#include <hip/hip_runtime.h>

// Problem constants (fixed by the reference file).
#define DIN  4096
#define NG   4096          // NUM_GATES = DOUT/3
#define BS   4096
#define RPB  8             // rows per block -> 512 blocks (2 generations/CU)
#define BT   1024          // 16 waves; 4 gates per thread covers all 4096 gates

typedef float v4f __attribute__((ext_vector_type(4)));

// out[b,g] = w0*x[b,(3g+1)&4095] + w1*x[b,(3g+2)&4095] + w2*x[b,(3g+3)&4095] + w3
// (w0..w3) = softmax(wgts[g,0,0..3]). Reference's signals[:, :, ::3] selects only
// row 0 of M = [1,0,0,0,0] -> out = s[...,0]; v4/v5 and rows 1..2 are dead code.
//
// R18: thread-private register pipeline, FULLY COMPILER-TRACKED, structure
// pinned by sched_barrier(0). No LDS, no s_barrier, no inline-asm vmem ops,
// no manual vmcnt.
//  - Ledger: tracked kernels are always CORRECT (R8/R11/R12/R13/R17); asm-load
//    kernels corrupted 3x (R14/R15/R16) -> asm vmem abandoned. Fast tracked
//    kernels need the pipeline to survive to the ISA: R10's register pipeline
//    died because the scheduler SANK the prefetch loads to their uses
//    (VGPR=32). Fix here: __builtin_amdgcn_sched_barrier(0) between the
//    prefetch loads and the compute — a compile-time fence nothing crosses,
//    so the loads stay issued early, and the compiler's OWN auto-waitcnt
//    before consumption is exactly counted (it tracks these loads).
//  - Barrier-free LDS rings are dead (R12: 42 us, R17: 46 us + FETCH 90 MB):
//    compiler serializes DMA->ds_read distance except in R8/R13's exact
//    4-object+barrier shape (28.6 us). This kernel has no DMA at all.
//  - Layout (R15's, proven aligned): thread t owns gates 4t..4t+3; inputs =
//    window floats 12t+1..12t+12, covered by 4 aligned dwordx4 loads at byte
//    offsets (48t+16k) & 16383 (mod never splits a 16B load). The 3x overlap
//    between neighbor threads dedupes in the CU's own L1 (row = 16 KiB);
//    each row is fetched from HBM by exactly one CU -> fetch-once.
//  - 2-row pipeline: load row r+1 into set B (4 loads), fence, compute row r
//    from set A, 1 nontemporal dwordx4 store (coalesced 16 B/lane).
//  - In-flight: 16 waves/CU x 4 KB = 16 KB > ~7.2 KB bandwidth-delay product
//    per CU at loaded HBM latency.
__global__ __launch_bounds__(BT, 4) void fredkin_schedpipe(
    const float* __restrict__ x,
    const float* __restrict__ wgts,
    float* __restrict__ out)
{
    const int tid = threadIdx.x;
    const int brow = blockIdx.x * RPB;

    // Softmax of wgts[g,0,:] for gates g = 4t+k (float offset 12g, 16B
    // aligned). Consumed before the pipeline; compiler orders its own waits.
    float4 wq[4];
#pragma unroll
    for (int k = 0; k < 4; ++k) {
        const int g = (tid << 2) + k;
        float4 r = *reinterpret_cast<const float4*>(wgts + (size_t)g * 12);
        float m  = fmaxf(fmaxf(r.x, r.y), fmaxf(r.z, r.w));
        float e0 = __expf(r.x - m);
        float e1 = __expf(r.y - m);
        float e2 = __expf(r.z - m);
        float e3 = __expf(r.w - m);
        float inv = 1.0f / (e0 + e1 + e2 + e3);
        wq[k] = make_float4(e0 * inv, e1 * inv, e2 * inv, e3 * inv);
    }

    // Row-invariant wrapped byte offsets of the 4 window float4s.
    unsigned vo[4];
#pragma unroll
    for (int k = 0; k < 4; ++k) vo[k] = (48u * tid + 16u * k) & 16383u;

    v4f a[4];   // row r   register set (constant-indexed, fully unrolled)
    v4f b[4];   // row r+1 register set

#define LOADROW(P, R_)                                                        \
    {                                                                         \
        const char* xr_ = reinterpret_cast<const char*>(                      \
            x + (size_t)(brow + (R_)) * DIN);                                 \
        P[0] = *reinterpret_cast<const v4f*>(xr_ + vo[0]);                    \
        P[1] = *reinterpret_cast<const v4f*>(xr_ + vo[1]);                    \
        P[2] = *reinterpret_cast<const v4f*>(xr_ + vo[2]);                    \
        P[3] = *reinterpret_cast<const v4f*>(xr_ + vo[3]);                    \
    }

    // Gate k inputs = window floats 3k+1..3k+3:
    // k0: P0.yzw | k1: P1.xyz | k2: P1.w P2.xy | k3: P2.zw P3.x
#define COMPROW(P, R_)                                                        \
    {                                                                         \
        v4f o_;                                                               \
        o_.x = fmaf(wq[0].x, P[0].y, fmaf(wq[0].y, P[0].z, fmaf(wq[0].z, P[0].w, wq[0].w))); \
        o_.y = fmaf(wq[1].x, P[1].x, fmaf(wq[1].y, P[1].y, fmaf(wq[1].z, P[1].z, wq[1].w))); \
        o_.z = fmaf(wq[2].x, P[1].w, fmaf(wq[2].y, P[2].x, fmaf(wq[2].z, P[2].y, wq[2].w))); \
        o_.w = fmaf(wq[3].x, P[2].z, fmaf(wq[3].y, P[2].w, fmaf(wq[3].z, P[3].x, wq[3].w))); \
        float* orow_ = out + (size_t)(brow + (R_)) * NG + (tid << 2);         \
        __builtin_nontemporal_store(o_, reinterpret_cast<v4f*>(orow_));       \
    }

    // Pipeline iteration: issue row r+1's loads, FENCE (nothing crosses:
    // loads can't sink, FMAs can't hoist), compute row r. The compiler
    // inserts its own exactly-counted s_waitcnt before the first use of CUR
    // (tracked loads -> correct by construction).
#define FRED_ITER(R_, CUR, NXT, DO_LOAD)                                      \
    {                                                                         \
        if (DO_LOAD) LOADROW(NXT, (R_) + 1)                                   \
        __builtin_amdgcn_sched_barrier(0);                                    \
        COMPROW(CUR, R_)                                                      \
        __builtin_amdgcn_sched_barrier(0);                                    \
    }

    LOADROW(a, 0)                 // prologue: row 0 in flight
    __builtin_amdgcn_sched_barrier(0);

    FRED_ITER(0, a, b, 1)
    FRED_ITER(1, b, a, 1)
    FRED_ITER(2, a, b, 1)
    FRED_ITER(3, b, a, 1)
    FRED_ITER(4, a, b, 1)
    FRED_ITER(5, b, a, 1)
    FRED_ITER(6, a, b, 1)
    FRED_ITER(7, b, a, 0)
#undef FRED_ITER
#undef COMPROW
#undef LOADROW
}

extern "C" void kernel_launch(void* const* d_in, const int* in_sizes, int n_in,
                              void* d_out, int out_size, void* d_ws, size_t ws_size,
                              hipStream_t stream) {
    const float* x    = (const float*)d_in[0];   // (BS, DIN) fp32
    const float* wgts = (const float*)d_in[1];   // (NG, 3, 4) fp32
    // d_in[2] (connections) is deterministic: (3g+1+j) % DIN — computed inline.
    float* out = (float*)d_out;                  // (BS, NG) fp32

    fredkin_schedpipe<<<dim3(BS / RPB), dim3(BT), 0, stream>>>(x, wgts, out);
}